// Round 4
// baseline (273.059 us; speedup 1.0000x reference)
//
#include <hip/hip_runtime.h>
#include <hip/hip_cooperative_groups.h>
#include <math.h>

namespace cg = cooperative_groups;

// 2-layer GCN, scalar-per-node form, ZERO global atomics, ONE cooperative
// kernel with grid-wide syncs between phases:
//   P0 hist : per-block LDS histogram of coarse bucket (dst>>8) -> bh[bucket][blk]
//   P1 scan : (block 0) per-bucket exclusive prefix over blocks + bucket bases
//   P2 bin  : re-read edges; pos = buckbase[b]+bh[b][blk]+LDS-rank;
//             packed[pos] = (src<<8)|(dst&255)          (plain stores)
//   P3 deg  : per bucket LDS int hist -> dinv = rsqrt(1+deg), g = dinv*x
//   P4 l1   : per bucket LDS float acc of g[src] -> u = dinv*h2(dinv*(acc+g))
//   P5 l2   : per bucket LDS float acc of u[src] -> out = sigmoid(dinv*(acc+u)+b2)

#define G    256   // blocks (co-resident: 4 waves/block on 256 CUs)
#define TB   256   // threads per block
#define MAXB 2048  // max coarse buckets the LDS buffer supports

__global__ void gcn_all(const int* __restrict__ src, const int* __restrict__ dst,
                        const float* __restrict__ x,
                        const float* __restrict__ W1, const float* __restrict__ b1,
                        const float* __restrict__ W2, const float* __restrict__ b2,
                        int* __restrict__ bh, int* __restrict__ buckbase,
                        int* __restrict__ packed,
                        float* __restrict__ dinv, float* __restrict__ g,
                        float* __restrict__ u, float* __restrict__ out,
                        int n, int e, int nb, int ec, int K) {
    cg::grid_group grid = cg::this_grid();
    __shared__ int sh[MAXB];
    float* shf = (float*)sh;
    const int t = threadIdx.x;
    const int blk = blockIdx.x;

    // ---- P0: histogram of coarse buckets, per edge-chunk ----
    for (int i = t; i < nb; i += TB) sh[i] = 0;
    __syncthreads();
    {
        int start = blk * ec, end = min(e, start + ec);
        for (int i = start + t; i < end; i += TB)
            atomicAdd(&sh[dst[i] >> 8], 1);
    }
    __syncthreads();
    for (int i = t; i < nb; i += TB) bh[(size_t)i * G + blk] = sh[i];  // transposed
    grid.sync();

    // ---- P1: scans (block 0 only; rows are contiguous) ----
    if (blk == 0) {
        for (int b = t; b < nb; b += TB) {
            int* row = bh + (size_t)b * G;
            int run = 0;
#pragma unroll 4
            for (int k = 0; k < G; ++k) { int c = row[k]; row[k] = run; run += c; }
            sh[b] = run;                       // bucket total
        }
        __syncthreads();
        if (t == 0) {
            int acc = 0;
            for (int b = 0; b < nb; ++b) { int v = sh[b]; sh[b] = acc; acc += v; }
        }
        __syncthreads();
        for (int b = t; b < nb; b += TB) buckbase[b] = sh[b];
        if (t == 0) buckbase[nb] = e;
    }
    grid.sync();

    // ---- P2: bin edges into bucket-sorted packed[] ----
    for (int i = t; i < nb; i += TB) sh[i] = buckbase[i] + bh[(size_t)i * G + blk];
    __syncthreads();
    {
        int start = blk * ec, end = min(e, start + ec);
        for (int i = start + t; i < end; i += TB) {
            int d = dst[i];
            int s = src[i];
            int p = atomicAdd(&sh[d >> 8], 1);          // LDS atomic only
            packed[p] = (s << 8) | (d & 255);
        }
    }
    grid.sync();

    // ---- P3: degree -> dinv, g ----
    for (int b = blk; b < nb; b += G) {
        __syncthreads();
        sh[t] = 0;
        __syncthreads();
        int s0 = buckbase[b], s1 = buckbase[b + 1];
        for (int j = s0 + t; j < s1; j += TB)
            atomicAdd(&sh[packed[j] & 255], 1);
        __syncthreads();
        int node = (b << 8) + t;
        if (node < n) {
            float di = rsqrtf(1.0f + (float)sh[t]);
            dinv[node] = di;
            g[node] = di * x[node];
        }
    }
    grid.sync();

    // ---- P4: layer 1 aggregate + 35-term sigmoid mix -> u ----
    for (int b = blk; b < nb; b += G) {
        __syncthreads();
        shf[t] = 0.f;
        __syncthreads();
        int s0 = buckbase[b], s1 = buckbase[b + 1];
        for (int j = s0 + t; j < s1; j += TB) {
            int pk = packed[j];
            atomicAdd(&shf[pk & 255], g[pk >> 8]);      // LDS float atomic
        }
        __syncthreads();
        int node = (b << 8) + t;
        if (node < n) {
            float di = dinv[node];
            float tt = di * (shf[t] + g[node]);
            float h2 = 0.f;
            for (int k = 0; k < K; ++k) {
                float z = fmaf(W1[k], tt, b1[k]);
                h2 = fmaf(__fdividef(1.f, 1.f + __expf(-z)), W2[k], h2);
            }
            u[node] = di * h2;
        }
    }
    grid.sync();

    // ---- P5: layer 2 aggregate -> out ----
    for (int b = blk; b < nb; b += G) {
        __syncthreads();
        shf[t] = 0.f;
        __syncthreads();
        int s0 = buckbase[b], s1 = buckbase[b + 1];
        for (int j = s0 + t; j < s1; j += TB) {
            int pk = packed[j];
            atomicAdd(&shf[pk & 255], u[pk >> 8]);
        }
        __syncthreads();
        int node = (b << 8) + t;
        if (node < n) {
            float z = fmaf(dinv[node], shf[t] + u[node], b2[0]);
            out[node] = __fdividef(1.f, 1.f + __expf(-z));
        }
    }
}

// ---------------- fallback (round-1 atomic path, 3n floats) ----------------
__global__ void f_init(float* __restrict__ deg, int n) {
    int i = blockIdx.x * 256 + threadIdx.x;
    if (i < n) deg[i] = 1.0f;
}
__global__ void f_degree(const int* __restrict__ dst, float* __restrict__ deg, int e) {
    int i = blockIdx.x * 256 + threadIdx.x;
    if (i < e) atomicAdd(&deg[dst[i]], 1.0f);
}
__global__ void f_node1(const float* __restrict__ x, float* dd,
                        float* __restrict__ g, float* __restrict__ s, int n) {
    int i = blockIdx.x * 256 + threadIdx.x;
    if (i < n) {
        float di = rsqrtf(dd[i]);
        dd[i] = di;
        float gi = di * x[i];
        g[i] = gi; s[i] = gi;
    }
}
__global__ void f_scatter(const int* __restrict__ src, const int* __restrict__ dst,
                          const float* __restrict__ g, float* __restrict__ s, int e) {
    int i = blockIdx.x * 256 + threadIdx.x;
    if (i < e) atomicAdd(&s[dst[i]], g[src[i]]);
}
__global__ void f_node2(const float* __restrict__ dinv, const float* s,
                        const float* __restrict__ W1, const float* __restrict__ b1,
                        const float* __restrict__ W2, float* u, float* r, int n, int K) {
    int i = blockIdx.x * 256 + threadIdx.x;
    if (i < n) {
        float tt = dinv[i] * s[i];
        float h2 = 0.f;
        for (int k = 0; k < K; ++k) {
            float z = fmaf(W1[k], tt, b1[k]);
            h2 = fmaf(__fdividef(1.f, 1.f + __expf(-z)), W2[k], h2);
        }
        float ui = dinv[i] * h2;
        u[i] = ui; r[i] = ui;
    }
}
__global__ void f_out(const float* __restrict__ dinv, const float* __restrict__ r,
                      const float* __restrict__ b2, float* __restrict__ out, int n) {
    int i = blockIdx.x * 256 + threadIdx.x;
    if (i < n) {
        float z = fmaf(dinv[i], r[i], b2[0]);
        out[i] = __fdividef(1.f, 1.f + __expf(-z));
    }
}

extern "C" void kernel_launch(void* const* d_in, const int* in_sizes, int n_in,
                              void* d_out, int out_size, void* d_ws, size_t ws_size,
                              hipStream_t stream) {
    const float* x  = (const float*)d_in[0];
    const int*   ei = (const int*)d_in[1];
    const float* W1 = (const float*)d_in[2];
    const float* b1 = (const float*)d_in[3];
    const float* W2 = (const float*)d_in[4];
    const float* b2 = (const float*)d_in[5];

    const int n = in_sizes[0];
    const int e = in_sizes[1] / 2;
    const int K = in_sizes[2];
    const int* src = ei;
    const int* dst = ei + e;
    float* out = (float*)d_out;

    const int nb = (n + 255) >> 8;      // coarse buckets (256 nodes each)
    const int ec = (e + G - 1) / G;     // edges per block chunk

    // ws: bh[nb*G] buckbase[nb+1] packed[e] dinv[n] g[n] u[n]
    size_t need = ((size_t)nb * G + nb + 1 + (size_t)e + 3 * (size_t)n) * 4;

    if (nb <= MAXB && ws_size >= need) {
        int* bh       = (int*)d_ws;
        int* buckbase = bh + (size_t)nb * G;
        int* packed   = buckbase + nb + 1;
        float* dinv   = (float*)(packed + e);
        float* g      = dinv + n;
        float* u      = g + n;

        void* args[] = {(void*)&src, (void*)&dst, (void*)&x,
                        (void*)&W1, (void*)&b1, (void*)&W2, (void*)&b2,
                        (void*)&bh, (void*)&buckbase, (void*)&packed,
                        (void*)&dinv, (void*)&g, (void*)&u, (void*)&out,
                        (void*)&n, (void*)&e, (void*)&nb, (void*)&ec, (void*)&K};
        hipLaunchCooperativeKernel((void*)gcn_all, dim3(G), dim3(TB), args, 0, stream);
    } else {
        float* A = (float*)d_ws;
        float* B = A + n;
        float* C = B + n;
        const int bn = (n + 255) / 256;
        const int be = (e + 255) / 256;
        f_init   <<<bn, 256, 0, stream>>>(A, n);
        f_degree <<<be, 256, 0, stream>>>(dst, A, e);
        f_node1  <<<bn, 256, 0, stream>>>(x, A, B, C, n);
        f_scatter<<<be, 256, 0, stream>>>(src, dst, B, C, e);
        f_node2  <<<bn, 256, 0, stream>>>(A, C, W1, b1, W2, B, C, n, K);
        f_scatter<<<be, 256, 0, stream>>>(src, dst, B, C, e);
        f_out    <<<bn, 256, 0, stream>>>(A, C, b2, out, n);
    }
}

// Round 5
// 116.700 us; speedup vs baseline: 2.3398x; 2.3398x over previous
//
#include <hip/hip_runtime.h>
#include <math.h>

// 2-layer GCN, scalar-per-node form, zero global atomics, multi-kernel
// (round-3 structure) with parallelism fixes:
//   - fine buckets: 64 nodes (dst>>6), nb = ceil(n/64) blocks for node phases
//   - edge phases: NBLK=512 blocks, int4-vectorized edge reads
//   - 4-way banked LDS accumulators in the per-bucket reduce phases
// Pipeline: hist -> colscan -> bscan -> bin -> deg -> l1 -> l2

#define NBLK 512   // edge-phase blocks (hist/bin must match chunking)
#define TB   256
#define MAXB 4096  // max fine buckets (LDS: nb*4 bytes in hist/bin)

__global__ void k_hist(const int* __restrict__ dst, int* __restrict__ bh,
                       int e, int ec, int nb) {
    extern __shared__ int sh[];
    const int t = threadIdx.x, blk = blockIdx.x;
    for (int i = t; i < nb; i += TB) sh[i] = 0;
    __syncthreads();
    int start = blk * ec, end = min(e, start + ec);
    int tile = start;
    for (; tile + TB * 4 <= end; tile += TB * 4) {
        const int4 d4 = *reinterpret_cast<const int4*>(dst + tile + t * 4);
        atomicAdd(&sh[d4.x >> 6], 1);
        atomicAdd(&sh[d4.y >> 6], 1);
        atomicAdd(&sh[d4.z >> 6], 1);
        atomicAdd(&sh[d4.w >> 6], 1);
    }
    for (int i = tile + t; i < end; i += TB) atomicAdd(&sh[dst[i] >> 6], 1);
    __syncthreads();
    for (int i = t; i < nb; i += TB) bh[(size_t)i * NBLK + blk] = sh[i];  // transposed
}

__global__ void k_colscan(int* __restrict__ bh, int* __restrict__ bucktot, int nb) {
    int b = blockIdx.x * TB + threadIdx.x;
    if (b >= nb) return;
    int* row = bh + (size_t)b * NBLK;
    int run = 0;
#pragma unroll 8
    for (int k = 0; k < NBLK; ++k) { int c = row[k]; row[k] = run; run += c; }
    bucktot[b] = run;
}

__global__ void k_bscan(const int* __restrict__ bucktot, int* __restrict__ buckbase,
                        int nb, int e) {
    __shared__ int sh[1024];
    const int t = threadIdx.x;
    int v[4];
    int tsum = 0;
#pragma unroll
    for (int j = 0; j < 4; ++j) {
        int idx = t * 4 + j;
        int c = (idx < nb) ? bucktot[idx] : 0;
        v[j] = tsum; tsum += c;
    }
    sh[t] = tsum;
    __syncthreads();
    for (int off = 1; off < 1024; off <<= 1) {
        int w = (t >= off) ? sh[t - off] : 0;
        __syncthreads();
        sh[t] += w;
        __syncthreads();
    }
    int ex = sh[t] - tsum;
#pragma unroll
    for (int j = 0; j < 4; ++j) {
        int idx = t * 4 + j;
        if (idx < nb) buckbase[idx] = ex + v[j];
    }
    if (t == 0) buckbase[nb] = e;
}

__global__ void k_bin(const int* __restrict__ src, const int* __restrict__ dst,
                      const int* __restrict__ bh, const int* __restrict__ buckbase,
                      int* __restrict__ packed, int e, int ec, int nb) {
    extern __shared__ int pos[];
    const int t = threadIdx.x, blk = blockIdx.x;
    for (int i = t; i < nb; i += TB) pos[i] = buckbase[i] + bh[(size_t)i * NBLK + blk];
    __syncthreads();
    int start = blk * ec, end = min(e, start + ec);
    int tile = start;
    for (; tile + TB * 4 <= end; tile += TB * 4) {
        const int4 s4 = *reinterpret_cast<const int4*>(src + tile + t * 4);
        const int4 d4 = *reinterpret_cast<const int4*>(dst + tile + t * 4);
        int p;
        p = atomicAdd(&pos[d4.x >> 6], 1); packed[p] = (s4.x << 6) | (d4.x & 63);
        p = atomicAdd(&pos[d4.y >> 6], 1); packed[p] = (s4.y << 6) | (d4.y & 63);
        p = atomicAdd(&pos[d4.z >> 6], 1); packed[p] = (s4.z << 6) | (d4.z & 63);
        p = atomicAdd(&pos[d4.w >> 6], 1); packed[p] = (s4.w << 6) | (d4.w & 63);
    }
    for (int i = tile + t; i < end; i += TB) {
        int d = dst[i], s = src[i];
        int p = atomicAdd(&pos[d >> 6], 1);
        packed[p] = (s << 6) | (d & 63);
    }
}

__global__ void k_deg(const int* __restrict__ packed, const int* __restrict__ buckbase,
                      const float* __restrict__ x, float* __restrict__ dinv,
                      float* __restrict__ g, int n) {
    __shared__ int cnt[256];
    const int t = threadIdx.x, b = blockIdx.x;
    cnt[t] = 0;
    __syncthreads();
    const int bank = (t & 3) << 6;
    int s0 = buckbase[b], s1 = buckbase[b + 1];
    for (int j = s0 + t; j < s1; j += TB)
        atomicAdd(&cnt[bank | (packed[j] & 63)], 1);
    __syncthreads();
    if (t < 64) {
        int node = (b << 6) + t;
        if (node < n) {
            int c = cnt[t] + cnt[64 + t] + cnt[128 + t] + cnt[192 + t];
            float di = rsqrtf(1.0f + (float)c);
            dinv[node] = di;
            g[node] = di * x[node];
        }
    }
}

__global__ void k_l1(const int* __restrict__ packed, const int* __restrict__ buckbase,
                     const float* __restrict__ g, const float* __restrict__ dinv,
                     const float* __restrict__ W1, const float* __restrict__ b1,
                     const float* __restrict__ W2, float* __restrict__ u, int n, int K) {
    __shared__ float acc[256];
    const int t = threadIdx.x, b = blockIdx.x;
    acc[t] = 0.f;
    __syncthreads();
    const int bank = (t & 3) << 6;
    int s0 = buckbase[b], s1 = buckbase[b + 1];
    for (int j = s0 + t; j < s1; j += TB) {
        int pk = packed[j];
        atomicAdd(&acc[bank | (pk & 63)], g[pk >> 6]);   // LDS float atomic
    }
    __syncthreads();
    if (t < 64) {
        int node = (b << 6) + t;
        if (node < n) {
            float s = acc[t] + acc[64 + t] + acc[128 + t] + acc[192 + t];
            float di = dinv[node];
            float tt = di * (s + g[node]);
            float h2 = 0.f;
            for (int k = 0; k < K; ++k) {
                float z = fmaf(W1[k], tt, b1[k]);
                h2 = fmaf(__fdividef(1.f, 1.f + __expf(-z)), W2[k], h2);
            }
            u[node] = di * h2;
        }
    }
}

__global__ void k_l2(const int* __restrict__ packed, const int* __restrict__ buckbase,
                     const float* __restrict__ u, const float* __restrict__ dinv,
                     const float* __restrict__ b2, float* __restrict__ out, int n) {
    __shared__ float acc[256];
    const int t = threadIdx.x, b = blockIdx.x;
    acc[t] = 0.f;
    __syncthreads();
    const int bank = (t & 3) << 6;
    int s0 = buckbase[b], s1 = buckbase[b + 1];
    for (int j = s0 + t; j < s1; j += TB) {
        int pk = packed[j];
        atomicAdd(&acc[bank | (pk & 63)], u[pk >> 6]);
    }
    __syncthreads();
    if (t < 64) {
        int node = (b << 6) + t;
        if (node < n) {
            float s = acc[t] + acc[64 + t] + acc[128 + t] + acc[192 + t];
            float z = fmaf(dinv[node], s + u[node], b2[0]);
            out[node] = __fdividef(1.f, 1.f + __expf(-z));
        }
    }
}

// ---------------- fallback (round-1 atomic path, 3n floats) ----------------
__global__ void f_init(float* __restrict__ deg, int n) {
    int i = blockIdx.x * 256 + threadIdx.x;
    if (i < n) deg[i] = 1.0f;
}
__global__ void f_degree(const int* __restrict__ dst, float* __restrict__ deg, int e) {
    int i = blockIdx.x * 256 + threadIdx.x;
    if (i < e) atomicAdd(&deg[dst[i]], 1.0f);
}
__global__ void f_node1(const float* __restrict__ x, float* dd,
                        float* __restrict__ g, float* __restrict__ s, int n) {
    int i = blockIdx.x * 256 + threadIdx.x;
    if (i < n) {
        float di = rsqrtf(dd[i]);
        dd[i] = di;
        float gi = di * x[i];
        g[i] = gi; s[i] = gi;
    }
}
__global__ void f_scatter(const int* __restrict__ src, const int* __restrict__ dst,
                          const float* __restrict__ g, float* __restrict__ s, int e) {
    int i = blockIdx.x * 256 + threadIdx.x;
    if (i < e) atomicAdd(&s[dst[i]], g[src[i]]);
}
__global__ void f_node2(const float* __restrict__ dinv, const float* s,
                        const float* __restrict__ W1, const float* __restrict__ b1,
                        const float* __restrict__ W2, float* u, float* r, int n, int K) {
    int i = blockIdx.x * 256 + threadIdx.x;
    if (i < n) {
        float tt = dinv[i] * s[i];
        float h2 = 0.f;
        for (int k = 0; k < K; ++k) {
            float z = fmaf(W1[k], tt, b1[k]);
            h2 = fmaf(__fdividef(1.f, 1.f + __expf(-z)), W2[k], h2);
        }
        float ui = dinv[i] * h2;
        u[i] = ui; r[i] = ui;
    }
}
__global__ void f_out(const float* __restrict__ dinv, const float* __restrict__ r,
                      const float* __restrict__ b2, float* __restrict__ out, int n) {
    int i = blockIdx.x * 256 + threadIdx.x;
    if (i < n) {
        float z = fmaf(dinv[i], r[i], b2[0]);
        out[i] = __fdividef(1.f, 1.f + __expf(-z));
    }
}

extern "C" void kernel_launch(void* const* d_in, const int* in_sizes, int n_in,
                              void* d_out, int out_size, void* d_ws, size_t ws_size,
                              hipStream_t stream) {
    const float* x  = (const float*)d_in[0];
    const int*   ei = (const int*)d_in[1];
    const float* W1 = (const float*)d_in[2];
    const float* b1 = (const float*)d_in[3];
    const float* W2 = (const float*)d_in[4];
    const float* b2 = (const float*)d_in[5];

    const int n = in_sizes[0];
    const int e = in_sizes[1] / 2;
    const int K = in_sizes[2];
    const int* src = ei;
    const int* dst = ei + e;
    float* out = (float*)d_out;

    const int nb = (n + 63) >> 6;                       // fine buckets (64 nodes)
    const int ec = (((e + NBLK - 1) / NBLK) + 3) & ~3;  // edges/block, mult of 4

    // ws: bh[nb*NBLK] bucktot[nb] buckbase[nb+1] packed[e] dinv[n] g[n] u[n]
    size_t need = ((size_t)nb * NBLK + 2 * (size_t)nb + 1 + (size_t)e + 3 * (size_t)n) * 4;

    if (nb <= MAXB && ws_size >= need) {
        int* bh       = (int*)d_ws;
        int* bucktot  = bh + (size_t)nb * NBLK;
        int* buckbase = bucktot + nb;
        int* packed   = buckbase + nb + 1;
        float* dinv   = (float*)(packed + e);
        float* g      = dinv + n;
        float* u      = g + n;

        k_hist   <<<NBLK, TB, nb * 4, stream>>>(dst, bh, e, ec, nb);
        k_colscan<<<(nb + TB - 1) / TB, TB, 0, stream>>>(bh, bucktot, nb);
        k_bscan  <<<1, 1024, 0, stream>>>(bucktot, buckbase, nb, e);
        k_bin    <<<NBLK, TB, nb * 4, stream>>>(src, dst, bh, buckbase, packed, e, ec, nb);
        k_deg    <<<nb, TB, 0, stream>>>(packed, buckbase, x, dinv, g, n);
        k_l1     <<<nb, TB, 0, stream>>>(packed, buckbase, g, dinv, W1, b1, W2, u, n, K);
        k_l2     <<<nb, TB, 0, stream>>>(packed, buckbase, u, dinv, b2, out, n);
    } else {
        float* A = (float*)d_ws;
        float* B = A + n;
        float* C = B + n;
        const int bn = (n + 255) / 256;
        const int be = (e + 255) / 256;
        f_init   <<<bn, 256, 0, stream>>>(A, n);
        f_degree <<<be, 256, 0, stream>>>(dst, A, e);
        f_node1  <<<bn, 256, 0, stream>>>(x, A, B, C, n);
        f_scatter<<<be, 256, 0, stream>>>(src, dst, B, C, e);
        f_node2  <<<bn, 256, 0, stream>>>(A, C, W1, b1, W2, B, C, n, K);
        f_scatter<<<be, 256, 0, stream>>>(src, dst, B, C, e);
        f_out    <<<bn, 256, 0, stream>>>(A, C, b2, out, n);
    }
}

// Round 6
// 72.936 us; speedup vs baseline: 3.7438x; 1.6000x over previous
//
#include <hip/hip_runtime.h>
#include <math.h>

// 2-layer GCN, scalar-per-node form, zero global atomics.
// Pipeline: hist -> colscan(wave-parallel) -> bscan -> bin -> deg -> l1 -> l2
//   - fine buckets: 64 nodes (dst>>6), nb = ceil(n/64)
//   - edge phases: NBLK=1024 blocks, int4 reads, XCD-aware chunk remap
//   - colscan: one wave per bucket row (fixes round-5's 44us 7-block scan)

#define NBLK 1024  // edge-phase blocks; bh row length (must be 64*16)
#define TB   256
#define MAXB 4096  // max fine buckets (LDS: nb*4 bytes in hist/bin)

__device__ __forceinline__ int chunk_of(int blk) {
    // consecutive chunks -> same XCD (dispatch round-robins blk%8 across XCDs)
    return ((blk & 7) * (NBLK >> 3)) + (blk >> 3);
}

__global__ void k_hist(const int* __restrict__ dst, int* __restrict__ bh,
                       int e, int ec, int nb) {
    extern __shared__ int sh[];
    const int t = threadIdx.x;
    const int chunk = chunk_of(blockIdx.x);
    for (int i = t; i < nb; i += TB) sh[i] = 0;
    __syncthreads();
    int start = chunk * ec, end = min(e, start + ec);
    int tile = start;
    for (; tile + TB * 4 <= end; tile += TB * 4) {
        const int4 d4 = *reinterpret_cast<const int4*>(dst + tile + t * 4);
        atomicAdd(&sh[d4.x >> 6], 1);
        atomicAdd(&sh[d4.y >> 6], 1);
        atomicAdd(&sh[d4.z >> 6], 1);
        atomicAdd(&sh[d4.w >> 6], 1);
    }
    for (int i = tile + t; i < end; i += TB) atomicAdd(&sh[dst[i] >> 6], 1);
    __syncthreads();
    for (int i = t; i < nb; i += TB) bh[(size_t)i * NBLK + chunk] = sh[i];
}

// One wave per bucket row: lane owns 16 contiguous ints; lane-local prefix +
// shfl_up wave scan. Rows are contiguous (transposed bh) -> coalesced int4.
__global__ void k_colscan(int* __restrict__ bh, int* __restrict__ bucktot, int nb) {
    const int lane = threadIdx.x & 63;
    const int wid = threadIdx.x >> 6;
    const int b = blockIdx.x * 4 + wid;
    if (b >= nb) return;
    int4* row = reinterpret_cast<int4*>(bh + (size_t)b * NBLK + lane * 16);
    int4 v0 = row[0], v1 = row[1], v2 = row[2], v3 = row[3];
    int s = v0.x + v0.y + v0.z + v0.w + v1.x + v1.y + v1.z + v1.w
          + v2.x + v2.y + v2.z + v2.w + v3.x + v3.y + v3.z + v3.w;
    int inc = s;
#pragma unroll
    for (int off = 1; off < 64; off <<= 1) {
        int w = __shfl_up(inc, off, 64);
        if (lane >= off) inc += w;
    }
    int run = inc - s;  // wave-exclusive base for this lane
    int c;
    c = v0.x; v0.x = run; run += c;  c = v0.y; v0.y = run; run += c;
    c = v0.z; v0.z = run; run += c;  c = v0.w; v0.w = run; run += c;
    c = v1.x; v1.x = run; run += c;  c = v1.y; v1.y = run; run += c;
    c = v1.z; v1.z = run; run += c;  c = v1.w; v1.w = run; run += c;
    c = v2.x; v2.x = run; run += c;  c = v2.y; v2.y = run; run += c;
    c = v2.z; v2.z = run; run += c;  c = v2.w; v2.w = run; run += c;
    c = v3.x; v3.x = run; run += c;  c = v3.y; v3.y = run; run += c;
    c = v3.z; v3.z = run; run += c;  c = v3.w; v3.w = run; run += c;
    row[0] = v0; row[1] = v1; row[2] = v2; row[3] = v3;
    if (lane == 63) bucktot[b] = inc;
}

__global__ void k_bscan(const int* __restrict__ bucktot, int* __restrict__ buckbase,
                        int nb, int e) {
    __shared__ int sh[1024];
    const int t = threadIdx.x;
    int v[4];
    int tsum = 0;
#pragma unroll
    for (int j = 0; j < 4; ++j) {
        int idx = t * 4 + j;
        int c = (idx < nb) ? bucktot[idx] : 0;
        v[j] = tsum; tsum += c;
    }
    sh[t] = tsum;
    __syncthreads();
    for (int off = 1; off < 1024; off <<= 1) {
        int w = (t >= off) ? sh[t - off] : 0;
        __syncthreads();
        sh[t] += w;
        __syncthreads();
    }
    int ex = sh[t] - tsum;
#pragma unroll
    for (int j = 0; j < 4; ++j) {
        int idx = t * 4 + j;
        if (idx < nb) buckbase[idx] = ex + v[j];
    }
    if (t == 0) buckbase[nb] = e;
}

__global__ void k_bin(const int* __restrict__ src, const int* __restrict__ dst,
                      const int* __restrict__ bh, const int* __restrict__ buckbase,
                      int* __restrict__ packed, int e, int ec, int nb) {
    extern __shared__ int pos[];
    const int t = threadIdx.x;
    const int chunk = chunk_of(blockIdx.x);
    for (int i = t; i < nb; i += TB) pos[i] = buckbase[i] + bh[(size_t)i * NBLK + chunk];
    __syncthreads();
    int start = chunk * ec, end = min(e, start + ec);
    int tile = start;
    for (; tile + TB * 4 <= end; tile += TB * 4) {
        const int4 s4 = *reinterpret_cast<const int4*>(src + tile + t * 4);
        const int4 d4 = *reinterpret_cast<const int4*>(dst + tile + t * 4);
        int p;
        p = atomicAdd(&pos[d4.x >> 6], 1); packed[p] = (s4.x << 6) | (d4.x & 63);
        p = atomicAdd(&pos[d4.y >> 6], 1); packed[p] = (s4.y << 6) | (d4.y & 63);
        p = atomicAdd(&pos[d4.z >> 6], 1); packed[p] = (s4.z << 6) | (d4.z & 63);
        p = atomicAdd(&pos[d4.w >> 6], 1); packed[p] = (s4.w << 6) | (d4.w & 63);
    }
    for (int i = tile + t; i < end; i += TB) {
        int d = dst[i], s = src[i];
        int p = atomicAdd(&pos[d >> 6], 1);
        packed[p] = (s << 6) | (d & 63);
    }
}

__global__ void k_deg(const int* __restrict__ packed, const int* __restrict__ buckbase,
                      const float* __restrict__ x, float* __restrict__ dinv,
                      float* __restrict__ g, int n) {
    __shared__ int cnt[256];
    const int t = threadIdx.x, b = blockIdx.x;
    cnt[t] = 0;
    __syncthreads();
    const int bank = (t & 3) << 6;
    int s0 = buckbase[b], s1 = buckbase[b + 1];
    for (int j = s0 + t; j < s1; j += TB)
        atomicAdd(&cnt[bank | (packed[j] & 63)], 1);
    __syncthreads();
    if (t < 64) {
        int node = (b << 6) + t;
        if (node < n) {
            int c = cnt[t] + cnt[64 + t] + cnt[128 + t] + cnt[192 + t];
            float di = rsqrtf(1.0f + (float)c);
            dinv[node] = di;
            g[node] = di * x[node];
        }
    }
}

__global__ void k_l1(const int* __restrict__ packed, const int* __restrict__ buckbase,
                     const float* __restrict__ g, const float* __restrict__ dinv,
                     const float* __restrict__ W1, const float* __restrict__ b1,
                     const float* __restrict__ W2, float* __restrict__ u, int n, int K) {
    __shared__ float acc[256];
    const int t = threadIdx.x, b = blockIdx.x;
    acc[t] = 0.f;
    __syncthreads();
    const int bank = (t & 3) << 6;
    int s0 = buckbase[b], s1 = buckbase[b + 1];
    for (int j = s0 + t; j < s1; j += TB) {
        int pk = packed[j];
        atomicAdd(&acc[bank | (pk & 63)], g[pk >> 6]);   // LDS float atomic
    }
    __syncthreads();
    if (t < 64) {
        int node = (b << 6) + t;
        if (node < n) {
            float s = acc[t] + acc[64 + t] + acc[128 + t] + acc[192 + t];
            float di = dinv[node];
            float tt = di * (s + g[node]);
            float h2 = 0.f;
            for (int k = 0; k < K; ++k) {
                float z = fmaf(W1[k], tt, b1[k]);
                h2 = fmaf(__fdividef(1.f, 1.f + __expf(-z)), W2[k], h2);
            }
            u[node] = di * h2;
        }
    }
}

__global__ void k_l2(const int* __restrict__ packed, const int* __restrict__ buckbase,
                     const float* __restrict__ u, const float* __restrict__ dinv,
                     const float* __restrict__ b2, float* __restrict__ out, int n) {
    __shared__ float acc[256];
    const int t = threadIdx.x, b = blockIdx.x;
    acc[t] = 0.f;
    __syncthreads();
    const int bank = (t & 3) << 6;
    int s0 = buckbase[b], s1 = buckbase[b + 1];
    for (int j = s0 + t; j < s1; j += TB) {
        int pk = packed[j];
        atomicAdd(&acc[bank | (pk & 63)], u[pk >> 6]);
    }
    __syncthreads();
    if (t < 64) {
        int node = (b << 6) + t;
        if (node < n) {
            float s = acc[t] + acc[64 + t] + acc[128 + t] + acc[192 + t];
            float z = fmaf(dinv[node], s + u[node], b2[0]);
            out[node] = __fdividef(1.f, 1.f + __expf(-z));
        }
    }
}

// ---------------- fallback (round-1 atomic path, 3n floats) ----------------
__global__ void f_init(float* __restrict__ deg, int n) {
    int i = blockIdx.x * 256 + threadIdx.x;
    if (i < n) deg[i] = 1.0f;
}
__global__ void f_degree(const int* __restrict__ dst, float* __restrict__ deg, int e) {
    int i = blockIdx.x * 256 + threadIdx.x;
    if (i < e) atomicAdd(&deg[dst[i]], 1.0f);
}
__global__ void f_node1(const float* __restrict__ x, float* dd,
                        float* __restrict__ g, float* __restrict__ s, int n) {
    int i = blockIdx.x * 256 + threadIdx.x;
    if (i < n) {
        float di = rsqrtf(dd[i]);
        dd[i] = di;
        float gi = di * x[i];
        g[i] = gi; s[i] = gi;
    }
}
__global__ void f_scatter(const int* __restrict__ src, const int* __restrict__ dst,
                          const float* __restrict__ g, float* __restrict__ s, int e) {
    int i = blockIdx.x * 256 + threadIdx.x;
    if (i < e) atomicAdd(&s[dst[i]], g[src[i]]);
}
__global__ void f_node2(const float* __restrict__ dinv, const float* s,
                        const float* __restrict__ W1, const float* __restrict__ b1,
                        const float* __restrict__ W2, float* u, float* r, int n, int K) {
    int i = blockIdx.x * 256 + threadIdx.x;
    if (i < n) {
        float tt = dinv[i] * s[i];
        float h2 = 0.f;
        for (int k = 0; k < K; ++k) {
            float z = fmaf(W1[k], tt, b1[k]);
            h2 = fmaf(__fdividef(1.f, 1.f + __expf(-z)), W2[k], h2);
        }
        float ui = dinv[i] * h2;
        u[i] = ui; r[i] = ui;
    }
}
__global__ void f_out(const float* __restrict__ dinv, const float* __restrict__ r,
                      const float* __restrict__ b2, float* __restrict__ out, int n) {
    int i = blockIdx.x * 256 + threadIdx.x;
    if (i < n) {
        float z = fmaf(dinv[i], r[i], b2[0]);
        out[i] = __fdividef(1.f, 1.f + __expf(-z));
    }
}

extern "C" void kernel_launch(void* const* d_in, const int* in_sizes, int n_in,
                              void* d_out, int out_size, void* d_ws, size_t ws_size,
                              hipStream_t stream) {
    const float* x  = (const float*)d_in[0];
    const int*   ei = (const int*)d_in[1];
    const float* W1 = (const float*)d_in[2];
    const float* b1 = (const float*)d_in[3];
    const float* W2 = (const float*)d_in[4];
    const float* b2 = (const float*)d_in[5];

    const int n = in_sizes[0];
    const int e = in_sizes[1] / 2;
    const int K = in_sizes[2];
    const int* src = ei;
    const int* dst = ei + e;
    float* out = (float*)d_out;

    const int nb = (n + 63) >> 6;                       // fine buckets (64 nodes)
    const int ec = (((e + NBLK - 1) / NBLK) + 3) & ~3;  // edges/chunk, mult of 4

    // ws: bh[nb*NBLK] bucktot[nb] buckbase[nb+1] packed[e] dinv[n] g[n] u[n]
    size_t need = ((size_t)nb * NBLK + 2 * (size_t)nb + 1 + (size_t)e + 3 * (size_t)n) * 4;

    if (nb <= MAXB && ws_size >= need) {
        int* bh       = (int*)d_ws;
        int* bucktot  = bh + (size_t)nb * NBLK;
        int* buckbase = bucktot + nb;
        int* packed   = buckbase + nb + 1;
        float* dinv   = (float*)(packed + e);
        float* g      = dinv + n;
        float* u      = g + n;

        k_hist   <<<NBLK, TB, nb * 4, stream>>>(dst, bh, e, ec, nb);
        k_colscan<<<(nb + 3) / 4, TB, 0, stream>>>(bh, bucktot, nb);
        k_bscan  <<<1, 1024, 0, stream>>>(bucktot, buckbase, nb, e);
        k_bin    <<<NBLK, TB, nb * 4, stream>>>(src, dst, bh, buckbase, packed, e, ec, nb);
        k_deg    <<<nb, TB, 0, stream>>>(packed, buckbase, x, dinv, g, n);
        k_l1     <<<nb, TB, 0, stream>>>(packed, buckbase, g, dinv, W1, b1, W2, u, n, K);
        k_l2     <<<nb, TB, 0, stream>>>(packed, buckbase, u, dinv, b2, out, n);
    } else {
        float* A = (float*)d_ws;
        float* B = A + n;
        float* C = B + n;
        const int bn = (n + 255) / 256;
        const int be = (e + 255) / 256;
        f_init   <<<bn, 256, 0, stream>>>(A, n);
        f_degree <<<be, 256, 0, stream>>>(dst, A, e);
        f_node1  <<<bn, 256, 0, stream>>>(x, A, B, C, n);
        f_scatter<<<be, 256, 0, stream>>>(src, dst, B, C, e);
        f_node2  <<<bn, 256, 0, stream>>>(A, C, W1, b1, W2, B, C, n, K);
        f_scatter<<<be, 256, 0, stream>>>(src, dst, B, C, e);
        f_out    <<<bn, 256, 0, stream>>>(A, C, b2, out, n);
    }
}